// Round 2
// baseline (4004.550 us; speedup 1.0000x reference)
//
#include <hip/hip_runtime.h>
#include <stdint.h>

#define D 800
#define NA 20000
#define NB 24000
#define NG 256

typedef unsigned short u16;
typedef __attribute__((ext_vector_type(8))) short s8v;
typedef __attribute__((ext_vector_type(4))) float f4v;

__device__ __forceinline__ float b2f(u16 u) {
  union { float f; uint32_t i; } x; x.i = ((uint32_t)u) << 16; return x.f;
}
__device__ __forceinline__ u16 f2b(float f) {
  union { float f; uint32_t i; } x; x.f = f;
  uint32_t r = x.i + 0x7fffu + ((x.i >> 16) & 1u);
  return (u16)(r >> 16);
}

__device__ __forceinline__ void async_cp16(const u16* g, u16* l) {
  __builtin_amdgcn_global_load_lds(
      (const __attribute__((address_space(1))) unsigned int*)(const void*)g,
      (__attribute__((address_space(3))) unsigned int*)(void*)l, 16, 0, 0);
}

// ---------------- f32 -> bf16 cast (float4 vectorized) ----------------------
__global__ __launch_bounds__(256) void castk(const float* __restrict__ x,
                                             u16* __restrict__ y, int n4) {
  const int i = blockIdx.x * 256 + threadIdx.x;
  if (i >= n4) return;
  const float4 v = ((const float4*)x)[i];
  ushort4 o;
  o.x = f2b(v.x); o.y = f2b(v.y); o.z = f2b(v.z); o.w = f2b(v.w);
  ((ushort4*)y)[i] = o;
}

// ---------------- GEMM: C[M,800] = A[M,800](bf16) @ W (+f32 bias) -----------
// BT pre-transposed bf16 weights [896,800] row-major (n-major, k contiguous),
// rows >=800 zero-padded.  mode 0: outb = bf16(acc+bias)
//                          mode 1: prev = bf16(0.8*prev + 0.2*(acc+bias))
//                          mode 2: outf  = acc + bscale*bias
//                          mode 3: outf += acc + bscale*bias
__global__ __launch_bounds__(256) void gemm_bt(
    const u16* __restrict__ A, const u16* __restrict__ BT,
    const float* __restrict__ bias, int M, int mode, float bscale,
    u16* __restrict__ outb, float* __restrict__ outf, u16* __restrict__ prev)
{
  __shared__ u16 sA[128 * 32];
  __shared__ u16 sB[128 * 32];
  const int tid  = threadIdx.x;
  const int row0 = blockIdx.x * 128;
  const int col0 = blockIdx.y * 128;
  const int ldRow = tid >> 2;
  const int ldCol = (tid & 3) * 8;
  const int w = tid >> 6, lane = tid & 63;
  const int wm = (w & 1) * 64, wn = (w >> 1) * 64;
  const int lr = lane & 15, quad = lane >> 4;

  f4v acc[4][4] = {};

  int ra = row0 + ldRow;      if (ra > M - 1) ra = M - 1;
  int rb = row0 + ldRow + 64; if (rb > M - 1) rb = M - 1;
  const u16* arow0 = A  + (size_t)ra * D + ldCol;
  const u16* arow1 = A  + (size_t)rb * D + ldCol;
  const u16* brow0 = BT + (size_t)(col0 + ldRow) * D + ldCol;
  const u16* brow1 = BT + (size_t)(col0 + ldRow + 64) * D + ldCol;
  u16* la0 = &sA[tid * 8];
  u16* la1 = &sA[2048 + tid * 8];
  u16* lb0 = &sB[tid * 8];
  u16* lb1 = &sB[2048 + tid * 8];

  for (int kt = 0; kt < 25; ++kt) {
    const int k0 = kt * 32;
    async_cp16(arow0 + k0, la0);
    async_cp16(arow1 + k0, la1);
    async_cp16(brow0 + k0, lb0);
    async_cp16(brow1 + k0, lb1);
    __syncthreads();
    s8v af[4], bf[4];
#pragma unroll
    for (int i = 0; i < 4; ++i)
      af[i] = *(const s8v*)&sA[(wm + i * 16 + lr) * 32 + quad * 8];
#pragma unroll
    for (int j = 0; j < 4; ++j)
      bf[j] = *(const s8v*)&sB[(wn + j * 16 + lr) * 32 + quad * 8];
#pragma unroll
    for (int i = 0; i < 4; ++i)
#pragma unroll
      for (int j = 0; j < 4; ++j)
        acc[i][j] = __builtin_amdgcn_mfma_f32_16x16x32_bf16(af[i], bf[j], acc[i][j], 0, 0, 0);
    __syncthreads();
  }

#pragma unroll
  for (int i = 0; i < 4; ++i) {
#pragma unroll
    for (int j = 0; j < 4; ++j) {
      const int col = col0 + wn + j * 16 + lr;
      if (col >= D) continue;
      const float bv = bias[col];
#pragma unroll
      for (int r = 0; r < 4; ++r) {
        const int row = row0 + wm + i * 16 + quad * 4 + r;
        if (row >= M) continue;
        const size_t idx = (size_t)row * D + col;
        const float v = acc[i][j][r];
        if (mode == 0) {
          outb[idx] = f2b(v + bv);
        } else if (mode == 1) {
          const float p = b2f(prev[idx]);
          prev[idx] = f2b(0.8f * p + 0.2f * (v + bv));
        } else if (mode == 2) {
          outf[idx] = v + bscale * bv;
        } else {
          outf[idx] += v + bscale * bv;
        }
      }
    }
  }
}

// -------- transpose+cast Ws[w] (f32 800x800 k-major) -> WT[w] (bf16 896x800)
__global__ void transpose_w(const float* __restrict__ W, u16* __restrict__ WT) {
  __shared__ u16 t[32][33];
  const int wm = blockIdx.z;
  const int k0 = blockIdx.x * 32, n0 = blockIdx.y * 32;
  const float* Wm = W + (size_t)wm * D * D;
  u16* Om = WT + (size_t)wm * 896 * D;
  const int tx = threadIdx.x, ty = threadIdx.y;
#pragma unroll
  for (int i = ty; i < 32; i += 8) {
    const int n = n0 + tx;
    t[i][tx] = (n < D) ? f2b(Wm[(size_t)(k0 + i) * D + n]) : (u16)0;
  }
  __syncthreads();
#pragma unroll
  for (int i = ty; i < 32; i += 8) {
    Om[(size_t)(n0 + i) * D + (k0 + tx)] = t[tx][i];
  }
}

// ---------------- e_pre[b] += Ah[ba0] + Ah[ba1] + Cu[bg]  (in-place, bf16) --
__global__ __launch_bounds__(256) void bond_combine(
    u16* __restrict__ epre, const u16* __restrict__ Ah, const u16* __restrict__ Cu,
    const int* __restrict__ ba, const int* __restrict__ bg)
{
  const int b = blockIdx.x;
  const int a0 = ba[b * 2], a1 = ba[b * 2 + 1], g = bg[b];
  const u16* r0 = Ah + (size_t)a0 * D;
  const u16* r1 = Ah + (size_t)a1 * D;
  const u16* rg = Cu + (size_t)g * D;
  u16* re = epre + (size_t)b * D;
  for (int j = threadIdx.x; j < D; j += 256) {
    re[j] = f2b(b2f(re[j]) + b2f(r0[j]) + b2f(r1[j]) + b2f(rg[j]));
  }
}

// ---------------- column sums / sumsq (atomic partials) ---------------------
__global__ __launch_bounds__(256) void col_stats(
    const void* __restrict__ x, int isf32, int M, int rpb, float* __restrict__ sums)
{
  const int col = blockIdx.x * 256 + threadIdx.x;
  if (col >= D) return;
  const int r0 = blockIdx.y * rpb;
  int r1 = r0 + rpb; if (r1 > M) r1 = M;
  float s = 0.f, ss = 0.f;
  if (isf32) {
    const float* xf = (const float*)x;
    for (int r = r0; r < r1; ++r) { const float v = xf[(size_t)r * D + col]; s += v; ss += v * v; }
  } else {
    const u16* xb = (const u16*)x;
    for (int r = r0; r < r1; ++r) { const float v = b2f(xb[(size_t)r * D + col]); s += v; ss += v * v; }
  }
  atomicAdd(&sums[col], s);
  atomicAdd(&sums[D + col], ss);
}

// ---------------- y = relu((x-mean)*rsqrt(var+eps)*g + b) -> f32 out --------
__global__ __launch_bounds__(256) void bn_relu(
    const void* __restrict__ x, int isf32, int M, int rpb, const float* __restrict__ sums,
    const float* __restrict__ gamma, const float* __restrict__ beta, float* __restrict__ out)
{
  const int col = blockIdx.x * 256 + threadIdx.x;
  if (col >= D) return;
  const float invM = 1.f / (float)M;
  const float mean = sums[col] * invM;
  float var = sums[D + col] * invM - mean * mean;
  if (var < 0.f) var = 0.f;
  const float rs = rsqrtf(var + 1e-5f);
  const float g = gamma[col] * rs;
  const float b = beta[col] - mean * g;
  const int r0 = blockIdx.y * rpb;
  int r1 = r0 + rpb; if (r1 > M) r1 = M;
  if (isf32) {
    const float* xf = (const float*)x;
    for (int r = r0; r < r1; ++r) {
      const float y = xf[(size_t)r * D + col] * g + b;
      out[(size_t)r * D + col] = (y > 0.f) ? y : 0.f;
    }
  } else {
    const u16* xb = (const u16*)x;
    for (int r = r0; r < r1; ++r) {
      const float y = b2f(xb[(size_t)r * D + col]) * g + b;
      out[(size_t)r * D + col] = (y > 0.f) ? y : 0.f;
    }
  }
}

// ---------------- gated mailbox aggregation + a2a + g2a ---------------------
__global__ __launch_bounds__(256) void atom_update(
    u16* __restrict__ hpre, const u16* __restrict__ Dh, const u16* __restrict__ Eh,
    const float* __restrict__ en, const u16* __restrict__ Fu,
    const int* __restrict__ ab, const int* __restrict__ ba, const int* __restrict__ ag)
{
  const int i = blockIdx.x;
  int bidx[4], oidx[4];
#pragma unroll
  for (int k = 0; k < 4; ++k) {
    const int b = ab[i * 4 + k];
    bidx[k] = b;
    const int p0 = ba[b * 2], p1 = ba[b * 2 + 1];
    oidx[k] = (p0 != i) ? p0 : p1;
  }
  const int g = ag[i];
  for (int j = threadIdx.x; j < D; j += 256) {
    float num = 0.f, den = 0.f;
#pragma unroll
    for (int k = 0; k < 4; ++k) {
      const float ev = en[(size_t)bidx[k] * D + j];
      const float s = 1.f / (1.f + __expf(-ev));
      num += s * b2f(Eh[(size_t)oidx[k] * D + j]);
      den += s;
    }
    const float v = b2f(Dh[(size_t)i * D + j]) + num / (den + 1e-6f) + b2f(Fu[(size_t)g * D + j]);
    hpre[(size_t)i * D + j] = f2b(v);
  }
}

// ---------------- c = 1/(|d1-d2|+1); cd1 = c*d1; cd2 = c*d2 (bf16 in/out) ---
__global__ __launch_bounds__(256) void cross_cd(
    const u16* __restrict__ D1, const u16* __restrict__ D2,
    u16* __restrict__ c1, u16* __restrict__ c2)
{
  const size_t t = (size_t)blockIdx.x * 256 + threadIdx.x;
  if (t >= (size_t)NA * D) return;
  const float d1 = b2f(D1[t]), d2 = b2f(D2[t]);
  const float c = 1.f / (fabsf(d1 - d2) + 1.f);
  c1[t] = f2b(c * d1);
  c2[t] = f2b(c * d2);
}

// ---------------- graph histogram (float counts) ----------------------------
__global__ void histo(const int* __restrict__ seg, int n, float* __restrict__ cnt) {
  const int i = blockIdx.x * 256 + threadIdx.x;
  if (i < n) atomicAdd(&cnt[seg[i]], 1.f);
}

// ---------------- LDS-privatized segment sum (f32 input) --------------------
#define SC 60
__global__ __launch_bounds__(256) void seg_sum(
    const float* __restrict__ x, const int* __restrict__ seg, int M, int rpb,
    float* __restrict__ out)
{
  __shared__ float acc[NG * SC];
  const int c0 = blockIdx.x * SC;
  for (int t = threadIdx.x; t < NG * SC; t += 256) acc[t] = 0.f;
  __syncthreads();
  const int lc = threadIdx.x % SC;
  const int lrr = threadIdx.x / SC;           // 0..4 (4 = idle tail)
  const int col = c0 + lc;
  const bool ok = (lrr < 4) && (col < D);
  const int r0 = blockIdx.y * rpb;
  int r1 = r0 + rpb; if (r1 > M) r1 = M;
  if (ok) {
    for (int r = r0 + lrr; r < r1; r += 4) {
      const int s = seg[r];
      atomicAdd(&acc[s * SC + lc], x[(size_t)r * D + col]);
    }
  }
  __syncthreads();
  for (int t = threadIdx.x; t < NG * SC; t += 256) {
    const int s = t / SC, c = c0 + (t % SC);
    const float v = acc[t];
    if (c < D && v != 0.f) atomicAdd(&out[(size_t)s * D + c], v);
  }
}

// ---------------- hbar12 / ebar12 (bf16) from segment sums + counts ---------
__global__ __launch_bounds__(256) void bar_prep(
    const float* __restrict__ hs1, const float* __restrict__ hs2,
    const float* __restrict__ ca1, const float* __restrict__ ca2,
    const float* __restrict__ es1, const float* __restrict__ es2,
    const float* __restrict__ cb1, const float* __restrict__ cb2,
    u16* __restrict__ hbar, u16* __restrict__ ebar)
{
  const int idx = blockIdx.x * 256 + threadIdx.x;
  if (idx >= NG * D) return;
  const int g = idx / D;
  const float h = hs1[idx] / fmaxf(ca1[g], 1.f) + hs2[idx] / fmaxf(ca2[g], 1.f);
  const float e = es1[idx] / fmaxf(cb1[g], 1.f) + es2[idx] / fmaxf(cb2[g], 1.f);
  hbar[idx] = f2b(h);
  ebar[idx] = f2b(e);
}

extern "C" void kernel_launch(void* const* d_in, const int* in_sizes, int n_in,
                              void* d_out, int out_size, void* d_ws, size_t ws_size,
                              hipStream_t stream)
{
  const float* h   = (const float*)d_in[0];
  const float* e   = (const float*)d_in[1];
  const float* h2  = (const float*)d_in[2];
  const float* e2  = (const float*)d_in[3];
  const float* u   = (const float*)d_in[4];
  const float* Ws  = (const float*)d_in[5];
  const float* bs  = (const float*)d_in[6];
  const float* gm  = (const float*)d_in[7];
  const float* bt  = (const float*)d_in[8];
  const int* ba1 = (const int*)d_in[9];
  const int* ab1 = (const int*)d_in[10];
  const int* ag1 = (const int*)d_in[11];
  const int* bg1 = (const int*)d_in[12];
  const int* ba2 = (const int*)d_in[13];
  const int* ab2 = (const int*)d_in[14];
  const int* ag2 = (const int*)d_in[15];
  const int* bg2 = (const int*)d_in[16];
  char* ws = (char*)d_ws;
  char* ob = (char*)d_out;

  // ---- workspace layout (bytes), ~160 MB total ----
  const size_t WT   = 0;                    // 10*896*800*2 = 14,336,000
  const size_t CB   = 14336000;             // 38,400,000 cast buf (later cd1)
  const size_t E1P  = 52736000;             // 38,400,000 (later h1pre)
  const size_t E2P  = 91136000;             // 38,400,000 (later h2pre)
  const size_t CD2  = 129536000;            // 32,000,000
  const size_t CUo  = 161536000;            // 409,600
  const size_t FUo  = 161945600;
  const size_t UB   = 162355200;
  const size_t F32Z = 162764800;            // zeroed fp32 scratch base
  const size_t ST_E1 = F32Z;
  const size_t ST_E2 = F32Z + 6400;
  const size_t ST_H1 = F32Z + 12800;
  const size_t ST_H2 = F32Z + 19200;
  const size_t ST_U  = F32Z + 25600;
  const size_t HS1  = F32Z + 32000;         // 819,200 each
  const size_t HS2  = HS1 + 819200;
  const size_t ES1  = HS2 + 819200;
  const size_t ES2  = ES1 + 819200;
  const size_t CNT  = ES2 + 819200;         // 4 x 1024 B float counts
  const size_t ZLEN = (CNT + 4096) - F32Z;
  const size_t UPRE = CNT + 4096;           // 819,200 fp32
  const size_t HBAR = UPRE + 819200;        // bf16
  const size_t EBAR = HBAR + 409600;

  u16* wt  = (u16*)(ws + WT);
  u16* cb  = (u16*)(ws + CB);
  u16* e1p = (u16*)(ws + E1P);
  u16* e2p = (u16*)(ws + E2P);
  u16* cd2 = (u16*)(ws + CD2);
  u16* cu  = (u16*)(ws + CUo);
  u16* fu  = (u16*)(ws + FUo);
  u16* ub  = (u16*)(ws + UB);
  u16* h1p = e1p;   // reuse (e1p dead after bn_relu e)
  u16* h2p = e2p;
  u16* cd1 = cb;    // reuse (cast buf dead after last gemm staging)

  // d_out regions (f32) + bf16 stashes inside not-yet-written regions
  float* o_h1 = (float*)ob;                       // [0, 64 MB)
  float* o_e1 = (float*)(ob + 64000000);          // [64, 140.8 MB)
  float* o_h2 = (float*)(ob + 140800000);         // [140.8, 204.8 MB)
  float* o_e2 = (float*)(ob + 204800000);         // [204.8, 281.6 MB)
  float* o_u  = (float*)(ob + 281600000);         // [281.6, 282.4 MB)
  u16* eh1s = (u16*)ob;                           // 32 MB, dead after atom_update
  u16* dh1s = (u16*)(ob + 32000000);              // 32 MB, dead after cross/mode1
  u16* eh2s = (u16*)(ob + 140800000);
  u16* dh2s = (u16*)(ob + 172800000);
  u16* ah1s = (u16*)(ob + 64000000);              // in o_e1, dead after bond_combine
  u16* ah2s = (u16*)(ob + 204800000);             // in o_e2

  auto gemm = [&](const u16* A, int widx, int M, int mode, float bsc,
                  u16* outb, float* outf, u16* prev) {
    dim3 grid((unsigned)((M + 127) / 128), 7);
    gemm_bt<<<grid, 256, 0, stream>>>(A, wt + (size_t)widx * 896 * D,
                                      bs + (size_t)widx * D, M, mode, bsc,
                                      outb, outf, prev);
  };

  hipMemsetAsync(ws + F32Z, 0, ZLEN, stream);
  transpose_w<<<dim3(25, 28, 10), dim3(32, 8), 0, stream>>>(Ws, wt);

  // u-linears (shared by both halves)
  castk<<<200, 256, 0, stream>>>(u, ub, NG * D / 4);
  gemm(ub, 2, NG, 0, 1.f, cu, nullptr, nullptr);   // Cu
  gemm(ub, 5, NG, 0, 1.f, fu, nullptr, nullptr);   // Fu

  // h-linears (cast buffer reused sequentially; stream ordering serializes)
  castk<<<15625, 256, 0, stream>>>(h, cb, NA * D / 4);
  gemm(cb, 0, NA, 0, 1.f, ah1s, nullptr, nullptr); // Ah1
  gemm(cb, 3, NA, 0, 1.f, dh1s, nullptr, nullptr); // Dh1
  gemm(cb, 4, NA, 0, 1.f, eh1s, nullptr, nullptr); // Eh1
  castk<<<15625, 256, 0, stream>>>(h2, cb, NA * D / 4);
  gemm(cb, 0, NA, 0, 1.f, ah2s, nullptr, nullptr); // Ah2
  gemm(cb, 3, NA, 0, 1.f, dh2s, nullptr, nullptr); // Dh2
  gemm(cb, 4, NA, 0, 1.f, eh2s, nullptr, nullptr); // Eh2
  castk<<<18750, 256, 0, stream>>>(e, cb, NB * D / 4);
  gemm(cb, 1, NB, 0, 1.f, e1p, nullptr, nullptr);  // Be1
  castk<<<18750, 256, 0, stream>>>(e2, cb, NB * D / 4);
  gemm(cb, 1, NB, 0, 1.f, e2p, nullptr, nullptr);  // Be2

  // bond update + BN + relu -> e1n/e2n (f32, clobbers Ah stashes after use)
  bond_combine<<<NB, 256, 0, stream>>>(e1p, ah1s, cu, ba1, bg1);
  bond_combine<<<NB, 256, 0, stream>>>(e2p, ah2s, cu, ba2, bg2);
  col_stats<<<dim3(4, 32), 256, 0, stream>>>(e1p, 0, NB, 750, (float*)(ws + ST_E1));
  col_stats<<<dim3(4, 32), 256, 0, stream>>>(e2p, 0, NB, 750, (float*)(ws + ST_E2));
  bn_relu<<<dim3(4, 32), 256, 0, stream>>>(e1p, 0, NB, 750, (float*)(ws + ST_E1), gm, bt, o_e1);
  bn_relu<<<dim3(4, 32), 256, 0, stream>>>(e2p, 0, NB, 750, (float*)(ws + ST_E2), gm, bt, o_e2);

  // atom update (h-pre overwrites dead e-pre buffers)
  atom_update<<<NA, 256, 0, stream>>>(h1p, dh1s, eh1s, o_e1, fu, ab1, ba1, ag1);
  atom_update<<<NA, 256, 0, stream>>>(h2p, dh2s, eh2s, o_e2, fu, ab2, ba2, ag2);

  // cross messages mixed in-place via GEMM epilogue
  cross_cd<<<62500, 256, 0, stream>>>(dh1s, dh2s, cd1, cd2);
  gemm(cd2, 9, NA, 1, 1.f, nullptr, nullptr, h1p); // h1 = 0.8 h1 + 0.2 m21
  gemm(cd1, 9, NA, 1, 1.f, nullptr, nullptr, h2p); // h2 = 0.8 h2 + 0.2 m12

  // BN + relu -> h1n/h2n (f32, clobbers Eh/Dh stashes, now dead)
  col_stats<<<dim3(4, 32), 256, 0, stream>>>(h1p, 0, NA, 625, (float*)(ws + ST_H1));
  col_stats<<<dim3(4, 32), 256, 0, stream>>>(h2p, 0, NA, 625, (float*)(ws + ST_H2));
  bn_relu<<<dim3(4, 32), 256, 0, stream>>>(h1p, 0, NA, 625, (float*)(ws + ST_H1), gm + D, bt + D, o_h1);
  bn_relu<<<dim3(4, 32), 256, 0, stream>>>(h2p, 0, NA, 625, (float*)(ws + ST_H2), gm + D, bt + D, o_h2);

  // global update: segment means first, then tiny GEMMs (linearity)
  histo<<<(NA + 255) / 256, 256, 0, stream>>>(ag1, NA, (float*)(ws + CNT));
  histo<<<(NA + 255) / 256, 256, 0, stream>>>(ag2, NA, (float*)(ws + CNT + 1024));
  histo<<<(NB + 255) / 256, 256, 0, stream>>>(bg1, NB, (float*)(ws + CNT + 2048));
  histo<<<(NB + 255) / 256, 256, 0, stream>>>(bg2, NB, (float*)(ws + CNT + 3072));
  seg_sum<<<dim3(14, 8), 256, 0, stream>>>(o_h1, ag1, NA, 2500, (float*)(ws + HS1));
  seg_sum<<<dim3(14, 8), 256, 0, stream>>>(o_h2, ag2, NA, 2500, (float*)(ws + HS2));
  seg_sum<<<dim3(14, 8), 256, 0, stream>>>(o_e1, bg1, NB, 3000, (float*)(ws + ES1));
  seg_sum<<<dim3(14, 8), 256, 0, stream>>>(o_e2, bg2, NB, 3000, (float*)(ws + ES2));
  bar_prep<<<800, 256, 0, stream>>>((float*)(ws + HS1), (float*)(ws + HS2),
                                    (float*)(ws + CNT), (float*)(ws + CNT + 1024),
                                    (float*)(ws + ES1), (float*)(ws + ES2),
                                    (float*)(ws + CNT + 2048), (float*)(ws + CNT + 3072),
                                    (u16*)(ws + HBAR), (u16*)(ws + EBAR));

  // u_pre = u@W8 + b8 + hbar12@W6 + 2*b6 + ebar12@W7 + 2*b7 (fp32 accum)
  gemm(ub,                8, NG, 2, 1.f, nullptr, (float*)(ws + UPRE), nullptr);
  gemm((u16*)(ws + HBAR), 6, NG, 3, 2.f, nullptr, (float*)(ws + UPRE), nullptr);
  gemm((u16*)(ws + EBAR), 7, NG, 3, 2.f, nullptr, (float*)(ws + UPRE), nullptr);

  col_stats<<<dim3(4, 1), 256, 0, stream>>>((float*)(ws + UPRE), 1, NG, 256, (float*)(ws + ST_U));
  bn_relu<<<dim3(4, 1), 256, 0, stream>>>((float*)(ws + UPRE), 1, NG, 256, (float*)(ws + ST_U),
                                          gm + 2 * D, bt + 2 * D, o_u);
}

// Round 3
// 2490.596 us; speedup vs baseline: 1.6079x; 1.6079x over previous
//
#include <hip/hip_runtime.h>
#include <stdint.h>

#define D 800
#define NA 20000
#define NB 24000
#define NG 256

typedef unsigned short u16;
typedef __attribute__((ext_vector_type(8))) short s8v;
typedef __attribute__((ext_vector_type(4))) float f4v;

__device__ __forceinline__ float b2f(u16 u) {
  union { float f; uint32_t i; } x; x.i = ((uint32_t)u) << 16; return x.f;
}
__device__ __forceinline__ u16 f2b(float f) {
  union { float f; uint32_t i; } x; x.f = f;
  uint32_t r = x.i + 0x7fffu + ((x.i >> 16) & 1u);
  return (u16)(r >> 16);
}

__device__ __forceinline__ void async_cp16(const u16* g, u16* l) {
  __builtin_amdgcn_global_load_lds(
      (const __attribute__((address_space(1))) unsigned int*)(const void*)g,
      (__attribute__((address_space(3))) unsigned int*)(void*)l, 16, 0, 0);
}

// ---------------- f32 -> bf16 cast (float4 vectorized) ----------------------
__global__ __launch_bounds__(256) void castk(const float* __restrict__ x,
                                             u16* __restrict__ y, int n4) {
  const int i = blockIdx.x * 256 + threadIdx.x;
  if (i >= n4) return;
  const float4 v = ((const float4*)x)[i];
  ushort4 o;
  o.x = f2b(v.x); o.y = f2b(v.y); o.z = f2b(v.z); o.w = f2b(v.w);
  ((ushort4*)y)[i] = o;
}

// ---------------- GEMM: C[M,800] = A[M,800](bf16) @ W (+f32 bias) -----------
__global__ __launch_bounds__(256) void gemm_bt(
    const u16* __restrict__ A, const u16* __restrict__ BT,
    const float* __restrict__ bias, int M, int mode, float bscale,
    u16* __restrict__ outb, float* __restrict__ outf, u16* __restrict__ prev)
{
  __shared__ u16 sA[128 * 32];
  __shared__ u16 sB[128 * 32];
  const int tid  = threadIdx.x;
  const int row0 = blockIdx.x * 128;
  const int col0 = blockIdx.y * 128;
  const int ldRow = tid >> 2;
  const int ldCol = (tid & 3) * 8;
  const int w = tid >> 6, lane = tid & 63;
  const int wm = (w & 1) * 64, wn = (w >> 1) * 64;
  const int lr = lane & 15, quad = lane >> 4;

  f4v acc[4][4] = {};

  int ra = row0 + ldRow;      if (ra > M - 1) ra = M - 1;
  int rb = row0 + ldRow + 64; if (rb > M - 1) rb = M - 1;
  const u16* arow0 = A  + (size_t)ra * D + ldCol;
  const u16* arow1 = A  + (size_t)rb * D + ldCol;
  const u16* brow0 = BT + (size_t)(col0 + ldRow) * D + ldCol;
  const u16* brow1 = BT + (size_t)(col0 + ldRow + 64) * D + ldCol;
  u16* la0 = &sA[tid * 8];
  u16* la1 = &sA[2048 + tid * 8];
  u16* lb0 = &sB[tid * 8];
  u16* lb1 = &sB[2048 + tid * 8];

  for (int kt = 0; kt < 25; ++kt) {
    const int k0 = kt * 32;
    async_cp16(arow0 + k0, la0);
    async_cp16(arow1 + k0, la1);
    async_cp16(brow0 + k0, lb0);
    async_cp16(brow1 + k0, lb1);
    __syncthreads();
    s8v af[4], bf[4];
#pragma unroll
    for (int i = 0; i < 4; ++i)
      af[i] = *(const s8v*)&sA[(wm + i * 16 + lr) * 32 + quad * 8];
#pragma unroll
    for (int j = 0; j < 4; ++j)
      bf[j] = *(const s8v*)&sB[(wn + j * 16 + lr) * 32 + quad * 8];
#pragma unroll
    for (int i = 0; i < 4; ++i)
#pragma unroll
      for (int j = 0; j < 4; ++j)
        acc[i][j] = __builtin_amdgcn_mfma_f32_16x16x32_bf16(af[i], bf[j], acc[i][j], 0, 0, 0);
    __syncthreads();
  }

#pragma unroll
  for (int i = 0; i < 4; ++i) {
#pragma unroll
    for (int j = 0; j < 4; ++j) {
      const int col = col0 + wn + j * 16 + lr;
      if (col >= D) continue;
      const float bv = bias[col];
#pragma unroll
      for (int r = 0; r < 4; ++r) {
        const int row = row0 + wm + i * 16 + quad * 4 + r;
        if (row >= M) continue;
        const size_t idx = (size_t)row * D + col;
        const float v = acc[i][j][r];
        if (mode == 0) {
          outb[idx] = f2b(v + bv);
        } else if (mode == 1) {
          const float p = b2f(prev[idx]);
          prev[idx] = f2b(0.8f * p + 0.2f * (v + bv));
        } else if (mode == 2) {
          outf[idx] = v + bscale * bv;
        } else {
          outf[idx] += v + bscale * bv;
        }
      }
    }
  }
}

// -------- transpose+cast Ws[w] (f32 800x800 k-major) -> WT[w] (bf16 896x800)
__global__ void transpose_w(const float* __restrict__ W, u16* __restrict__ WT) {
  __shared__ u16 t[32][33];
  const int wm = blockIdx.z;
  const int k0 = blockIdx.x * 32, n0 = blockIdx.y * 32;
  const float* Wm = W + (size_t)wm * D * D;
  u16* Om = WT + (size_t)wm * 896 * D;
  const int tx = threadIdx.x, ty = threadIdx.y;
#pragma unroll
  for (int i = ty; i < 32; i += 8) {
    const int n = n0 + tx;
    t[i][tx] = (n < D) ? f2b(Wm[(size_t)(k0 + i) * D + n]) : (u16)0;
  }
  __syncthreads();
#pragma unroll
  for (int i = ty; i < 32; i += 8) {
    Om[(size_t)(n0 + i) * D + (k0 + tx)] = t[tx][i];
  }
}

// ---------------- e_pre[b] += Ah[ba0] + Ah[ba1] + Cu[bg]  (in-place, bf16) --
__global__ __launch_bounds__(256) void bond_combine(
    u16* __restrict__ epre, const u16* __restrict__ Ah, const u16* __restrict__ Cu,
    const int* __restrict__ ba, const int* __restrict__ bg)
{
  const int b = blockIdx.x;
  const int a0 = ba[b * 2], a1 = ba[b * 2 + 1], g = bg[b];
  const u16* r0 = Ah + (size_t)a0 * D;
  const u16* r1 = Ah + (size_t)a1 * D;
  const u16* rg = Cu + (size_t)g * D;
  u16* re = epre + (size_t)b * D;
  for (int j = threadIdx.x; j < D; j += 256) {
    re[j] = f2b(b2f(re[j]) + b2f(r0[j]) + b2f(r1[j]) + b2f(rg[j]));
  }
}

// ---------------- column sums / sumsq (atomic partials) ---------------------
__global__ __launch_bounds__(256) void col_stats(
    const void* __restrict__ x, int isf32, int M, int rpb, float* __restrict__ sums)
{
  const int col = blockIdx.x * 256 + threadIdx.x;
  if (col >= D) return;
  const int r0 = blockIdx.y * rpb;
  int r1 = r0 + rpb; if (r1 > M) r1 = M;
  float s = 0.f, ss = 0.f;
  if (isf32) {
    const float* xf = (const float*)x;
    for (int r = r0; r < r1; ++r) { const float v = xf[(size_t)r * D + col]; s += v; ss += v * v; }
  } else {
    const u16* xb = (const u16*)x;
    for (int r = r0; r < r1; ++r) { const float v = b2f(xb[(size_t)r * D + col]); s += v; ss += v * v; }
  }
  atomicAdd(&sums[col], s);
  atomicAdd(&sums[D + col], ss);
}

// ---------------- y = relu((x-mean)*rsqrt(var+eps)*g + b) -> f32 out --------
__global__ __launch_bounds__(256) void bn_relu(
    const void* __restrict__ x, int isf32, int M, int rpb, const float* __restrict__ sums,
    const float* __restrict__ gamma, const float* __restrict__ beta, float* __restrict__ out)
{
  const int col = blockIdx.x * 256 + threadIdx.x;
  if (col >= D) return;
  const float invM = 1.f / (float)M;
  const float mean = sums[col] * invM;
  float var = sums[D + col] * invM - mean * mean;
  if (var < 0.f) var = 0.f;
  const float rs = rsqrtf(var + 1e-5f);
  const float g = gamma[col] * rs;
  const float b = beta[col] - mean * g;
  const int r0 = blockIdx.y * rpb;
  int r1 = r0 + rpb; if (r1 > M) r1 = M;
  if (isf32) {
    const float* xf = (const float*)x;
    for (int r = r0; r < r1; ++r) {
      const float y = xf[(size_t)r * D + col] * g + b;
      out[(size_t)r * D + col] = (y > 0.f) ? y : 0.f;
    }
  } else {
    const u16* xb = (const u16*)x;
    for (int r = r0; r < r1; ++r) {
      const float y = b2f(xb[(size_t)r * D + col]) * g + b;
      out[(size_t)r * D + col] = (y > 0.f) ? y : 0.f;
    }
  }
}

// ---------------- gated mailbox aggregation + a2a + g2a ---------------------
__global__ __launch_bounds__(256) void atom_update(
    u16* __restrict__ hpre, const u16* __restrict__ Dh, const u16* __restrict__ Eh,
    const float* __restrict__ en, const u16* __restrict__ Fu,
    const int* __restrict__ ab, const int* __restrict__ ba, const int* __restrict__ ag)
{
  const int i = blockIdx.x;
  int bidx[4], oidx[4];
#pragma unroll
  for (int k = 0; k < 4; ++k) {
    const int b = ab[i * 4 + k];
    bidx[k] = b;
    const int p0 = ba[b * 2], p1 = ba[b * 2 + 1];
    oidx[k] = (p0 != i) ? p0 : p1;
  }
  const int g = ag[i];
  for (int j = threadIdx.x; j < D; j += 256) {
    float num = 0.f, den = 0.f;
#pragma unroll
    for (int k = 0; k < 4; ++k) {
      const float ev = en[(size_t)bidx[k] * D + j];
      const float s = 1.f / (1.f + __expf(-ev));
      num += s * b2f(Eh[(size_t)oidx[k] * D + j]);
      den += s;
    }
    const float v = b2f(Dh[(size_t)i * D + j]) + num / (den + 1e-6f) + b2f(Fu[(size_t)g * D + j]);
    hpre[(size_t)i * D + j] = f2b(v);
  }
}

// ---------------- c = 1/(|d1-d2|+1); cd1 = c*d1; cd2 = c*d2 (bf16 in/out) ---
__global__ __launch_bounds__(256) void cross_cd(
    const u16* __restrict__ D1, const u16* __restrict__ D2,
    u16* __restrict__ c1, u16* __restrict__ c2)
{
  const size_t t = (size_t)blockIdx.x * 256 + threadIdx.x;
  if (t >= (size_t)NA * D) return;
  const float d1 = b2f(D1[t]), d2 = b2f(D2[t]);
  const float c = 1.f / (fabsf(d1 - d2) + 1.f);
  c1[t] = f2b(c * d1);
  c2[t] = f2b(c * d2);
}

// ============ counting-sort based segment mean (4 pipelines fused) ==========
// which: 0=h1(ag1,NA) 1=h2(ag2,NA) 2=e1(bg1,NB) 3=e2(bg2,NB)
__global__ void seg_histo(const int* __restrict__ s0, const int* __restrict__ s1,
                          const int* __restrict__ s2, const int* __restrict__ s3,
                          int* __restrict__ cnt) {
  const int which = blockIdx.y;
  const int* s = (which == 0) ? s0 : (which == 1) ? s1 : (which == 2) ? s2 : s3;
  const int n = (which < 2) ? NA : NB;
  const int i = blockIdx.x * 256 + threadIdx.x;
  if (i < n) atomicAdd(&cnt[which * NG + s[i]], 1);
}

__global__ __launch_bounds__(256) void seg_scan(
    const int* __restrict__ cnt, int* __restrict__ start, int* __restrict__ cursor) {
  const int which = blockIdx.x;
  __shared__ int buf[NG];
  const int t = threadIdx.x;
  const int v = cnt[which * NG + t];
  buf[t] = v;
  __syncthreads();
  int sum = 0;
  for (int i = 0; i < t; ++i) sum += buf[i];
  start[which * 257 + t] = sum;
  cursor[which * NG + t] = sum;
  if (t == NG - 1) start[which * 257 + NG] = sum + v;
}

__global__ void seg_scatter(const int* __restrict__ s0, const int* __restrict__ s1,
                            const int* __restrict__ s2, const int* __restrict__ s3,
                            int* __restrict__ cursor, int* __restrict__ order) {
  const int which = blockIdx.y;
  const int* s = (which == 0) ? s0 : (which == 1) ? s1 : (which == 2) ? s2 : s3;
  const int n = (which < 2) ? NA : NB;
  const int i = blockIdx.x * 256 + threadIdx.x;
  if (i < n) {
    const int pos = atomicAdd(&cursor[which * NG + s[i]], 1);
    order[which * NB + pos] = i;
  }
}

// block (g, which): mean over this graph's rows; coalesced f32 reads, no atomics
__global__ __launch_bounds__(256) void seg_reduce(
    const float* __restrict__ x0, const float* __restrict__ x1,
    const float* __restrict__ x2, const float* __restrict__ x3,
    const int* __restrict__ order, const int* __restrict__ start,
    float* __restrict__ means) {
  const int which = blockIdx.y;
  const float* x = (which == 0) ? x0 : (which == 1) ? x1 : (which == 2) ? x2 : x3;
  const int* ord = order + which * NB;
  const int g = blockIdx.x;
  const int i0 = start[which * 257 + g];
  const int i1 = start[which * 257 + g + 1];
  const int t = threadIdx.x;
  float a0 = 0.f, a1 = 0.f, a2 = 0.f, a3 = 0.f;
  for (int i = i0; i < i1; ++i) {
    const float* row = x + (size_t)ord[i] * D;
    a0 += row[t];
    a1 += row[t + 256];
    a2 += row[t + 512];
    if (t < 32) a3 += row[t + 768];
  }
  const int c = i1 - i0;
  const float inv = 1.f / (float)(c > 1 ? c : 1);
  float* o = means + ((size_t)which * NG + g) * D;
  o[t] = a0 * inv;
  o[t + 256] = a1 * inv;
  o[t + 512] = a2 * inv;
  if (t < 32) o[t + 768] = a3 * inv;
}

// hbar = bf16(mean_h1+mean_h2), ebar = bf16(mean_e1+mean_e2)
__global__ __launch_bounds__(256) void bar_prep(
    const float* __restrict__ means, u16* __restrict__ hbar, u16* __restrict__ ebar) {
  const int idx = blockIdx.x * 256 + threadIdx.x;
  if (idx >= NG * D) return;
  hbar[idx] = f2b(means[idx] + means[NG * D + idx]);
  ebar[idx] = f2b(means[2 * NG * D + idx] + means[3 * NG * D + idx]);
}

extern "C" void kernel_launch(void* const* d_in, const int* in_sizes, int n_in,
                              void* d_out, int out_size, void* d_ws, size_t ws_size,
                              hipStream_t stream)
{
  const float* h   = (const float*)d_in[0];
  const float* e   = (const float*)d_in[1];
  const float* h2  = (const float*)d_in[2];
  const float* e2  = (const float*)d_in[3];
  const float* u   = (const float*)d_in[4];
  const float* Ws  = (const float*)d_in[5];
  const float* bs  = (const float*)d_in[6];
  const float* gm  = (const float*)d_in[7];
  const float* bt  = (const float*)d_in[8];
  const int* ba1 = (const int*)d_in[9];
  const int* ab1 = (const int*)d_in[10];
  const int* ag1 = (const int*)d_in[11];
  const int* bg1 = (const int*)d_in[12];
  const int* ba2 = (const int*)d_in[13];
  const int* ab2 = (const int*)d_in[14];
  const int* ag2 = (const int*)d_in[15];
  const int* bg2 = (const int*)d_in[16];
  char* ws = (char*)d_ws;
  char* ob = (char*)d_out;

  // ---- workspace layout (bytes) ----
  const size_t WT   = 0;                    // 14,336,000
  const size_t CB   = 14336000;             // 38,400,000 cast buf / cd1 / sort bufs
  const size_t E1P  = 52736000;             // 38,400,000 (later h1pre)
  const size_t E2P  = 91136000;             // (later h2pre)
  const size_t CD2  = 129536000;            // 32,000,000
  const size_t CUo  = 161536000;
  const size_t FUo  = 161945600;
  const size_t UB   = 162355200;
  const size_t F32Z = 162764800;            // zeroed fp32 scratch base
  const size_t ST_E1 = F32Z;
  const size_t ST_E2 = F32Z + 6400;
  const size_t ST_H1 = F32Z + 12800;
  const size_t ST_H2 = F32Z + 19200;
  const size_t ST_U  = F32Z + 25600;
  const size_t ZLEN  = 32000;               // just the 5 stats blocks
  const size_t MEANS = F32Z + 32000;        // 4*256*800*4 = 3,276,800
  const size_t UPRE  = MEANS + 3276800;     // 819,200
  const size_t HBAR  = UPRE + 819200;       // bf16 409,600
  const size_t EBAR  = HBAR + 409600;
  // sort scratch inside CB region (dead after the mode-1 GEMMs)
  const size_t ORD  = CB;                   // 4*24000*4 = 384,000
  const size_t CNTI = CB + 400000;          // 4*256*4 = 4,096 (memset-zeroed)
  const size_t STRT = CB + 404496 + 3504;   // 4*257*4 = 4,112  (aligned region)
  const size_t CURS = CB + 416000;          // 4,096

  u16* wt  = (u16*)(ws + WT);
  u16* cb  = (u16*)(ws + CB);
  u16* e1p = (u16*)(ws + E1P);
  u16* e2p = (u16*)(ws + E2P);
  u16* cd2 = (u16*)(ws + CD2);
  u16* cu  = (u16*)(ws + CUo);
  u16* fu  = (u16*)(ws + FUo);
  u16* ub  = (u16*)(ws + UB);
  u16* h1p = e1p;
  u16* h2p = e2p;
  u16* cd1 = cb;

  float* o_h1 = (float*)ob;
  float* o_e1 = (float*)(ob + 64000000);
  float* o_h2 = (float*)(ob + 140800000);
  float* o_e2 = (float*)(ob + 204800000);
  float* o_u  = (float*)(ob + 281600000);
  u16* eh1s = (u16*)ob;
  u16* dh1s = (u16*)(ob + 32000000);
  u16* eh2s = (u16*)(ob + 140800000);
  u16* dh2s = (u16*)(ob + 172800000);
  u16* ah1s = (u16*)(ob + 64000000);
  u16* ah2s = (u16*)(ob + 204800000);

  auto gemm = [&](const u16* A, int widx, int M, int mode, float bsc,
                  u16* outb, float* outf, u16* prev) {
    dim3 grid((unsigned)((M + 127) / 128), 7);
    gemm_bt<<<grid, 256, 0, stream>>>(A, wt + (size_t)widx * 896 * D,
                                      bs + (size_t)widx * D, M, mode, bsc,
                                      outb, outf, prev);
  };

  hipMemsetAsync(ws + F32Z, 0, ZLEN, stream);
  transpose_w<<<dim3(25, 28, 10), dim3(32, 8), 0, stream>>>(Ws, wt);

  // u-linears (shared by both halves)
  castk<<<200, 256, 0, stream>>>(u, ub, NG * D / 4);
  gemm(ub, 2, NG, 0, 1.f, cu, nullptr, nullptr);   // Cu
  gemm(ub, 5, NG, 0, 1.f, fu, nullptr, nullptr);   // Fu

  // h/e linears (cast buffer reused sequentially)
  castk<<<15625, 256, 0, stream>>>(h, cb, NA * D / 4);
  gemm(cb, 0, NA, 0, 1.f, ah1s, nullptr, nullptr); // Ah1
  gemm(cb, 3, NA, 0, 1.f, dh1s, nullptr, nullptr); // Dh1
  gemm(cb, 4, NA, 0, 1.f, eh1s, nullptr, nullptr); // Eh1
  castk<<<15625, 256, 0, stream>>>(h2, cb, NA * D / 4);
  gemm(cb, 0, NA, 0, 1.f, ah2s, nullptr, nullptr); // Ah2
  gemm(cb, 3, NA, 0, 1.f, dh2s, nullptr, nullptr); // Dh2
  gemm(cb, 4, NA, 0, 1.f, eh2s, nullptr, nullptr); // Eh2
  castk<<<18750, 256, 0, stream>>>(e, cb, NB * D / 4);
  gemm(cb, 1, NB, 0, 1.f, e1p, nullptr, nullptr);  // Be1
  castk<<<18750, 256, 0, stream>>>(e2, cb, NB * D / 4);
  gemm(cb, 1, NB, 0, 1.f, e2p, nullptr, nullptr);  // Be2

  // bond update + BN + relu -> e1n/e2n
  bond_combine<<<NB, 256, 0, stream>>>(e1p, ah1s, cu, ba1, bg1);
  bond_combine<<<NB, 256, 0, stream>>>(e2p, ah2s, cu, ba2, bg2);
  col_stats<<<dim3(4, 64), 256, 0, stream>>>(e1p, 0, NB, 375, (float*)(ws + ST_E1));
  col_stats<<<dim3(4, 64), 256, 0, stream>>>(e2p, 0, NB, 375, (float*)(ws + ST_E2));
  bn_relu<<<dim3(4, 64), 256, 0, stream>>>(e1p, 0, NB, 375, (float*)(ws + ST_E1), gm, bt, o_e1);
  bn_relu<<<dim3(4, 64), 256, 0, stream>>>(e2p, 0, NB, 375, (float*)(ws + ST_E2), gm, bt, o_e2);

  // atom update
  atom_update<<<NA, 256, 0, stream>>>(h1p, dh1s, eh1s, o_e1, fu, ab1, ba1, ag1);
  atom_update<<<NA, 256, 0, stream>>>(h2p, dh2s, eh2s, o_e2, fu, ab2, ba2, ag2);

  // cross messages mixed in-place via GEMM epilogue
  cross_cd<<<62500, 256, 0, stream>>>(dh1s, dh2s, cd1, cd2);
  gemm(cd2, 9, NA, 1, 1.f, nullptr, nullptr, h1p); // h1 = 0.8 h1 + 0.2 m21
  gemm(cd1, 9, NA, 1, 1.f, nullptr, nullptr, h2p); // h2 = 0.8 h2 + 0.2 m12

  // BN + relu -> h1n/h2n
  col_stats<<<dim3(4, 64), 256, 0, stream>>>(h1p, 0, NA, 313, (float*)(ws + ST_H1));
  col_stats<<<dim3(4, 64), 256, 0, stream>>>(h2p, 0, NA, 313, (float*)(ws + ST_H2));
  bn_relu<<<dim3(4, 64), 256, 0, stream>>>(h1p, 0, NA, 313, (float*)(ws + ST_H1), gm + D, bt + D, o_h1);
  bn_relu<<<dim3(4, 64), 256, 0, stream>>>(h2p, 0, NA, 313, (float*)(ws + ST_H2), gm + D, bt + D, o_h2);

  // segment means via counting sort (CB region is dead now)
  hipMemsetAsync(ws + CNTI, 0, 4096, stream);
  seg_histo<<<dim3(94, 4), 256, 0, stream>>>(ag1, ag2, bg1, bg2, (int*)(ws + CNTI));
  seg_scan<<<4, 256, 0, stream>>>((int*)(ws + CNTI), (int*)(ws + STRT), (int*)(ws + CURS));
  seg_scatter<<<dim3(94, 4), 256, 0, stream>>>(ag1, ag2, bg1, bg2,
                                               (int*)(ws + CURS), (int*)(ws + ORD));
  seg_reduce<<<dim3(NG, 4), 256, 0, stream>>>(o_h1, o_h2, o_e1, o_e2,
                                              (int*)(ws + ORD), (int*)(ws + STRT),
                                              (float*)(ws + MEANS));
  bar_prep<<<800, 256, 0, stream>>>((float*)(ws + MEANS), (u16*)(ws + HBAR), (u16*)(ws + EBAR));

  // u_pre = u@W8 + b8 + hbar12@W6 + 2*b6 + ebar12@W7 + 2*b7 (fp32 accum)
  gemm(ub,                8, NG, 2, 1.f, nullptr, (float*)(ws + UPRE), nullptr);
  gemm((u16*)(ws + HBAR), 6, NG, 3, 2.f, nullptr, (float*)(ws + UPRE), nullptr);
  gemm((u16*)(ws + EBAR), 7, NG, 3, 2.f, nullptr, (float*)(ws + UPRE), nullptr);

  col_stats<<<dim3(4, 1), 256, 0, stream>>>((float*)(ws + UPRE), 1, NG, 256, (float*)(ws + ST_U));
  bn_relu<<<dim3(4, 1), 256, 0, stream>>>((float*)(ws + UPRE), 1, NG, 256, (float*)(ws + ST_U),
                                          gm + 2 * D, bt + 2 * D, o_u);
}